// Round 9
// baseline (515.506 us; speedup 1.0000x reference)
//
#include <hip/hip_runtime.h>
#include <hip/hip_bf16.h>
#include <hip/hip_cooperative_groups.h>

namespace cg = cooperative_groups;
using bf16 = __hip_bfloat16;
typedef __attribute__((ext_vector_type(8))) short short8;
typedef __attribute__((ext_vector_type(4))) float f32x4;

static __device__ __forceinline__ bf16 f2b(float x) { return __float2bfloat16(x); }
static __device__ __forceinline__ short fb(float x) {
  bf16 h = __float2bfloat16(fmaxf(x, 0.f));
  return *(short*)&h;
}

// async global->LDS, 16B per lane. Global src address is PER-LANE; LDS dest = uniform base + lane*16.
static __device__ __forceinline__ void gload_lds16(const void* g, void* l) {
  auto gp = (const __attribute__((address_space(1))) unsigned int*)g;
  auto lp = (__attribute__((address_space(3))) unsigned int*)l;
  __builtin_amdgcn_global_load_lds(gp, lp, 16, 0, 0);
}

struct MegaParams {
  const float *x, *sen, *w1, *b1, *w2, *b2, *w3, *b3, *w4, *b4;
  const float *g1w, *g1b, *g2w, *g2b, *g3w, *g3b;
  float* out;
  bf16 *p1, *p2, *p3, *Fe, *wuv, *w2r, *w3r, *w4r, *w2t, *w3t, *h2;
  float *uvws, *zbuf;
};

// ---------------- stage 0: prep task (conv1pool / scalar reorders / transposes) ----------------
static __device__ void prep_task(const MegaParams& P, int t, int tid, short* LA, short* LB) {
  if (t < 1536) {
    // conv1 + maxpool: NCHW f32 -> pooled NHWC bf16 [4][32][48][64]
    float* wl = (float*)LA;  // 1728 floats = 6.9 KB
    __syncthreads();  // protect LA from previous task's readers
    const int H = 64, W = 96, HW = H * W;
    for (int idx = tid; idx < 27 * 64; idx += 256) {
      int k = idx >> 6, oc_ = idx & 63;
      wl[idx] = P.w1[oc_ * 27 + k];
    }
    __syncthreads();
    int oc = tid & 63;
    int pp = t * 4 + (tid >> 6);
    int b = pp / 1536, rem = pp - b * 1536;
    int yp = rem / 48, xp = rem - yp * 48;
    int y0 = 2 * yp - 1, x0 = 2 * xp - 1;
    float win[3][4][4];
    #pragma unroll
    for (int ic = 0; ic < 3; ++ic) {
      const float* xsrc = P.x + ((size_t)b * 3 + ic) * HW;
      #pragma unroll
      for (int dy = 0; dy < 4; ++dy) {
        int yy = y0 + dy;
        #pragma unroll
        for (int dx = 0; dx < 4; ++dx) {
          int xx = x0 + dx;
          win[ic][dy][dx] = (yy >= 0 && yy < H && xx >= 0 && xx < W) ? xsrc[yy * W + xx] : 0.f;
        }
      }
    }
    float cmax = -1e30f;
    #pragma unroll
    for (int sy = 0; sy < 2; ++sy)
      #pragma unroll
      for (int sx = 0; sx < 2; ++sx) {
        float acc = 0.f;
        #pragma unroll
        for (int ic = 0; ic < 3; ++ic)
          #pragma unroll
          for (int ky = 0; ky < 3; ++ky)
            #pragma unroll
            for (int kx = 0; kx < 3; ++kx)
              acc += win[ic][sy + ky][sx + kx] * wl[(ic * 9 + ky * 3 + kx) * 64 + oc];
        cmax = fmaxf(cmax, acc);
      }
    P.p1[(size_t)pp * 64 + oc] = f2b(fmaxf(cmax + P.b1[oc], 0.f));
  } else if (t < 9601) {
    const int S1 = 73728, S2 = S1 + 294912, S3 = S2 + 1179648, S4 = S3 + 442368,
              S5 = S4 + 12288, S6 = S5 + 24576, S7 = S6 + 36864, S8 = S7 + 64;
    int i = (t - 1536) * 256 + tid;
    if (i < S1) {  // w2r: OC=128 IC=64, [oc][tap*IC+ic]
      int j = i, K = 576, IC = 64;
      int oc = j / K, r = j - oc * K, tap = r / IC, ic = r - tap * IC;
      P.w2r[j] = f2b(P.w2[((size_t)oc * IC + ic) * 9 + tap]);
    } else if (i < S2) {  // w3r
      int j = i - S1, K = 1152, IC = 128;
      int oc = j / K, r = j - oc * K, tap = r / IC, ic = r - tap * IC;
      P.w3r[j] = f2b(P.w3[((size_t)oc * IC + ic) * 9 + tap]);
    } else if (i < S3) {  // w4r
      int j = i - S2, K = 2304, IC = 256;
      int oc = j / K, r = j - oc * K, tap = r / IC, ic = r - tap * IC;
      P.w4r[j] = f2b(P.w4[((size_t)oc * IC + ic) * 9 + tap]);
    } else if (i < S4) {  // wuv[768][576]: [A^T ; Bm^T ; Cm^T]
      int j = i - S3;
      int n = j / 576, c = j - n * 576;
      float val = 0.f;
      if (n < 256)      { if (c < 514) val = P.g1w[(size_t)c * 256 + n]; }
      else if (n < 512) { if (c < 514) val = P.g1w[(size_t)(514 + c) * 256 + (n - 256)]; }
      else              { if (c < 384) val = P.g1w[(size_t)(1028 + c) * 256 + (n - 512)]; }
      P.wuv[j] = f2b(val);
    } else if (i < S5) {  // zero output accumulator (d_out)
      P.out[i - S4] = 0.f;
    } else if (i < S6) {  // Fe rows 0..383, cols 512..575
      int j = i - S5;
      int r = j >> 6, cc = j & 63;
      int p = r % 96;
      float val = 0.f;
      if (cc == 0) val = -1.0f + 2.0f * (float)(p / 8) / 11.0f;
      else if (cc == 1) val = -1.0f + 2.0f * (float)(p % 8) / 7.0f;
      P.Fe[(size_t)r * 576 + 512 + cc] = f2b(val);
    } else if (i < S7) {  // Fe rows 384..447: sen rows
      int j = i - S6;
      int r = j / 576, c = j - r * 576;
      float val = (r < 4 && c < 384) ? P.sen[r * 384 + c] : 0.f;
      P.Fe[(size_t)(384 + r) * 576 + c] = f2b(val);
    } else if (i < S8) {
      P.zbuf[i - S7] = 0.f;
    }
  } else {
    // transposes: g2w(256x256)->w2t, g3w(256x3072)->w3t
    bf16 (*tt)[33] = (bf16(*)[33])LB;
    __syncthreads();  // protect LB
    int b2 = t - 9601;
    const float* in;
    bf16* out;
    int R = 256, C, c0, r0;
    if (b2 < 64) { in = P.g2w; out = P.w2t; C = 256; c0 = (b2 & 7) * 32; r0 = (b2 >> 3) * 32; }
    else { b2 -= 64; in = P.g3w; out = P.w3t; C = 3072; c0 = (b2 % 96) * 32; r0 = (b2 / 96) * 32; }
    int xq = tid & 31, yq = tid >> 5;
    for (int yy = yq; yy < 32; yy += 8) {
      int r = r0 + yy, c = c0 + xq;
      if (r < R && c < C) tt[yy][xq] = f2b(in[(size_t)r * C + c]);
    }
    __syncthreads();
    for (int yy = yq; yy < 32; yy += 8) {
      int c = c0 + yy, r = r0 + xq;
      if (r < R && c < C) out[(size_t)c * R + r] = tt[xq][yy];
    }
  }
}

// ---------------- conv GEMM task: implicit im2col + fused pool, double-buffered ----------------
template <int CBITS, bool POOL>
static __device__ void conv_task(const bf16* pin, const bf16* Wt, const float* bias,
                                 bf16* outb, const bf16* zbuf, int Hi, int Wi, int N, int ldout,
                                 int nIdx, int mIdx, int tid, short* LA, short* LB) {
  const int C = 1 << CBITS;
  const int K = 9 << CBITS;
  int m0 = mIdx * 64, n0 = nIdx * 64;
  int w = tid >> 6, l = tid & 63;
  int quad = l >> 4, l16 = l & 15;
  f32x4 acc[4];
  #pragma unroll
  for (int nt = 0; nt < 4; ++nt)
    #pragma unroll
    for (int e = 0; e < 4; ++e) acc[nt][e] = 0.f;

  int lrow = l >> 3;
  int c_sw = (l & 7) ^ lrow;
  int ybase[2], xbase[2], bidx[2];
  #pragma unroll
  for (int i = 0; i < 2; ++i) {
    int row = m0 + w * 16 + i * 8 + lrow;
    if (POOL) {
      int pg = row >> 2, sub = row & 3;
      int Wh = Wi >> 1, HW2 = (Hi >> 1) * Wh;
      int b = pg / HW2, rem = pg - b * HW2;
      int py = rem / Wh, px = rem - py * Wh;
      bidx[i] = b; ybase[i] = 2 * py + (sub >> 1); xbase[i] = 2 * px + (sub & 1);
    } else {
      int HW = Hi * Wi;
      int b = row / HW, pix = row - b * HW;
      int yy = pix / Wi;
      bidx[i] = b; ybase[i] = yy; xbase[i] = pix - yy * Wi;
    }
  }
  const bf16* bg = Wt + (size_t)(n0 + w * 16 + lrow) * K + c_sw * 8;

  auto stage = [&](int kc, int buf) {
    int colt = kc + c_sw * 8;
    int tap = colt >> CBITS, cc = colt & (C - 1);
    int ty = tap / 3, tx = tap - 3 * ty;
    short* al = LA + buf * 4096 + ((size_t)w * 128 + l) * 8;
    short* bl = LB + buf * 4096 + ((size_t)w * 128 + l) * 8;
    #pragma unroll
    for (int i = 0; i < 2; ++i) {
      int yy = ybase[i] + ty - 1, xx = xbase[i] + tx - 1;
      const bf16* asrc = (yy >= 0 && yy < Hi && xx >= 0 && xx < Wi)
          ? pin + ((((size_t)(bidx[i] * Hi + yy)) * Wi + xx) << CBITS) + cc
          : zbuf;
      gload_lds16(asrc, al + i * 512);
      gload_lds16(bg + kc + (size_t)i * 8 * K, bl + i * 512);
    }
  };

  __syncthreads();  // protect LDS from previous task's readers
  stage(0, 0);
  const int NK = K >> 6;
  for (int ik = 0; ik < NK; ++ik) {
    int buf = ik & 1;
    __syncthreads();
    if (ik + 1 < NK) stage((ik + 1) * 64, buf ^ 1);
    #pragma unroll
    for (int ks = 0; ks < 64; ks += 32) {
      int cb = (ks >> 3) + quad;
      int mr = w * 16 + l16;
      short8 af = *(const short8*)&LA[buf * 4096 + mr * 64 + ((cb ^ (mr & 7)) * 8)];
      #pragma unroll
      for (int nt = 0; nt < 4; ++nt) {
        int nr = nt * 16 + l16;
        short8 bf2 = *(const short8*)&LB[buf * 4096 + nr * 64 + ((cb ^ (nr & 7)) * 8)];
        acc[nt] = __builtin_amdgcn_mfma_f32_16x16x32_bf16(af, bf2, acc[nt], 0, 0, 0);
      }
    }
  }
  if (POOL) {
    int pg = (m0 + w * 16 + quad * 4) >> 2;
    #pragma unroll
    for (int nt = 0; nt < 4; ++nt) {
      int gcol = n0 + nt * 16 + l16;
      float bv = bias[gcol];
      float m = fmaxf(fmaxf(acc[nt][0], acc[nt][1]), fmaxf(acc[nt][2], acc[nt][3]));
      outb[(size_t)pg * N + gcol] = f2b(fmaxf(m + bv, 0.f));
    }
  } else {
    #pragma unroll
    for (int nt = 0; nt < 4; ++nt) {
      int gcol = n0 + nt * 16 + l16;
      float bv = bias[gcol];
      #pragma unroll
      for (int r = 0; r < 4; ++r) {
        int grow = m0 + w * 16 + quad * 4 + r;
        outb[(size_t)grow * ldout + gcol] = f2b(fmaxf(acc[nt][r] + bv, 0.f));
      }
    }
  }
}

// ---------------- gemm64 task (uv head GEMM), double-buffered ----------------
static __device__ void gemm64_task(const bf16* A, const bf16* Wt, float* outf, int K, int ldout,
                                   int nIdx, int mIdx, int tid, short* LA, short* LB) {
  int m0 = mIdx * 64, n0 = nIdx * 64;
  int w = tid >> 6, l = tid & 63;
  int quad = l >> 4, l16 = l & 15;
  f32x4 acc[4];
  #pragma unroll
  for (int nt = 0; nt < 4; ++nt)
    #pragma unroll
    for (int e = 0; e < 4; ++e) acc[nt][e] = 0.f;

  int lrow = l >> 3;
  int c_sw = (l & 7) ^ lrow;
  const bf16* ag = A + (size_t)(m0 + w * 16 + lrow) * K + c_sw * 8;
  const bf16* bg = Wt + (size_t)(n0 + w * 16 + lrow) * K + c_sw * 8;

  auto stage = [&](int kc, int buf) {
    short* al = LA + buf * 4096 + ((size_t)w * 128 + l) * 8;
    short* bl = LB + buf * 4096 + ((size_t)w * 128 + l) * 8;
    #pragma unroll
    for (int i = 0; i < 2; ++i) {
      gload_lds16(ag + kc + (size_t)i * 8 * K, al + i * 512);
      gload_lds16(bg + kc + (size_t)i * 8 * K, bl + i * 512);
    }
  };

  __syncthreads();
  stage(0, 0);
  const int NK = K >> 6;
  for (int ik = 0; ik < NK; ++ik) {
    int buf = ik & 1;
    __syncthreads();
    if (ik + 1 < NK) stage((ik + 1) * 64, buf ^ 1);
    #pragma unroll
    for (int ks = 0; ks < 64; ks += 32) {
      int cb = (ks >> 3) + quad;
      int mr = w * 16 + l16;
      short8 af = *(const short8*)&LA[buf * 4096 + mr * 64 + ((cb ^ (mr & 7)) * 8)];
      #pragma unroll
      for (int nt = 0; nt < 4; ++nt) {
        int nr = nt * 16 + l16;
        short8 bf2 = *(const short8*)&LB[buf * 4096 + nr * 64 + ((cb ^ (nr & 7)) * 8)];
        acc[nt] = __builtin_amdgcn_mfma_f32_16x16x32_bf16(af, bf2, acc[nt], 0, 0, 0);
      }
    }
  }
  #pragma unroll
  for (int nt = 0; nt < 4; ++nt) {
    int gcol = n0 + nt * 16 + l16;
    #pragma unroll
    for (int r = 0; r < 4; ++r) {
      int grow = m0 + w * 16 + quad * 4 + r;
      outf[(size_t)grow * ldout + gcol] = acc[nt][r];
    }
  }
}

// ---------------- gemm2 task: h2 = relu(h1 @ W2 + b2); h1 formed on the fly ----------------
static __device__ void gemm2_task(const MegaParams& P, int t, int tid,
                                  short* LA, short* LB, float* wsl) {
  int nIdx = t & 1;
  int rest = t >> 1;
  int mIdx = rest % 72;
  int b = rest / 72;
  int m0 = mIdx * 128;
  int n0 = nIdx * 128;
  int w = tid >> 6, l = tid & 63;
  int quad = l >> 4, l16 = l & 15;
  int mw = (w >> 1) * 64, nw = (w & 1) * 64;
  f32x4 acc[4][4];
  #pragma unroll
  for (int i = 0; i < 4; ++i)
    #pragma unroll
    for (int j = 0; j < 4; ++j)
      #pragma unroll
      for (int e = 0; e < 4; ++e) acc[i][j][e] = 0.f;

  __syncthreads();  // protect LDS + wsl from previous task's readers
  wsl[tid] = P.uvws[(size_t)(384 + b) * 768 + 512 + tid] + P.g1b[tid];

  int lrow = l >> 3;
  int c_sw = (l & 7) ^ lrow;
  const bf16* bg = P.w2t + (size_t)(n0 + w * 32 + lrow) * 256 + c_sw * 8;
  short* bl = LB + ((size_t)w * 256 + l) * 8;

  int row = tid >> 1, ks0 = (tid & 1) * 32;
  int m = m0 + row;
  int i_idx = m / 96, j_idx = m - i_idx * 96;
  const float* up = P.uvws + (size_t)(b * 96 + j_idx) * 768 + ks0;
  const float* vp = P.uvws + (size_t)(b * 96 + i_idx) * 768 + 256 + ks0;
  __syncthreads();

  for (int kc = 0; kc < 256; kc += 64) {
    if (kc) __syncthreads();
    #pragma unroll
    for (int i = 0; i < 4; ++i)
      gload_lds16(bg + kc + (size_t)i * 8 * 256, bl + i * 512);
    {
      const float4* u4 = (const float4*)(up + kc);
      const float4* v4 = (const float4*)(vp + kc);
      const float4* w4 = (const float4*)&wsl[kc + ks0];
      #pragma unroll
      for (int ch = 0; ch < 4; ++ch) {
        short8 pack;
        #pragma unroll
        for (int q = 0; q < 2; ++q) {
          float4 uu = u4[ch * 2 + q], vv = v4[ch * 2 + q], ww = w4[ch * 2 + q];
          pack[q * 4 + 0] = fb(uu.x + vv.x + ww.x);
          pack[q * 4 + 1] = fb(uu.y + vv.y + ww.y);
          pack[q * 4 + 2] = fb(uu.z + vv.z + ww.z);
          pack[q * 4 + 3] = fb(uu.w + vv.w + ww.w);
        }
        int lc = (ks0 >> 3) + ch;
        *(short8*)&LA[row * 64 + ((lc ^ (row & 7)) * 8)] = pack;
      }
    }
    __syncthreads();
    #pragma unroll
    for (int ks = 0; ks < 64; ks += 32) {
      int cb = (ks >> 3) + quad;
      short8 af[4], bfr[4];
      #pragma unroll
      for (int mt = 0; mt < 4; ++mt) {
        int mr = mw + mt * 16 + l16;
        af[mt] = *(const short8*)&LA[mr * 64 + ((cb ^ (mr & 7)) * 8)];
      }
      #pragma unroll
      for (int nt = 0; nt < 4; ++nt) {
        int nr = nw + nt * 16 + l16;
        bfr[nt] = *(const short8*)&LB[nr * 64 + ((cb ^ (nr & 7)) * 8)];
      }
      #pragma unroll
      for (int mt = 0; mt < 4; ++mt)
        #pragma unroll
        for (int nt = 0; nt < 4; ++nt)
          acc[mt][nt] = __builtin_amdgcn_mfma_f32_16x16x32_bf16(af[mt], bfr[nt], acc[mt][nt], 0, 0, 0);
    }
  }
  bf16* h2b = P.h2 + (size_t)b * 9216 * 256;
  #pragma unroll
  for (int nt = 0; nt < 4; ++nt) {
    int gcol = n0 + nw + nt * 16 + l16;
    float bias = P.g2b[gcol];
    #pragma unroll
    for (int mt = 0; mt < 4; ++mt) {
      #pragma unroll
      for (int r = 0; r < 4; ++r) {
        int grow = m0 + mw + mt * 16 + quad * 4 + r;
        h2b[(size_t)grow * 256 + gcol] = f2b(fmaxf(acc[mt][nt][r] + bias, 0.f));
      }
    }
  }
}

// ---------------- gemm3 task: + relu + pair-sum, XCD-swizzled task id ----------------
static __device__ void gemm3_task(const MegaParams& P, int g, int tid, short* LA, short* LB) {
  int x = g & 7, s = g >> 3;
  int grp = s / 24;
  int nIdx = s - grp * 24;
  int mb = grp * 8 + x;
  int b = mb / 72;
  int m0 = (mb - b * 72) * 128;
  int n0 = nIdx * 128;
  int w = tid >> 6, l = tid & 63;
  int quad = l >> 4, l16 = l & 15;
  int mw = (w >> 1) * 64, nw = (w & 1) * 64;
  f32x4 acc[4][4];
  #pragma unroll
  for (int i = 0; i < 4; ++i)
    #pragma unroll
    for (int j = 0; j < 4; ++j)
      #pragma unroll
      for (int e = 0; e < 4; ++e) acc[i][j][e] = 0.f;

  const int K = 256;
  int lrow = l >> 3;
  int c_sw = (l & 7) ^ lrow;
  const bf16* ag = P.h2 + (size_t)(b * 9216 + m0 + w * 32 + lrow) * K + c_sw * 8;
  const bf16* bg = P.w3t + (size_t)(n0 + w * 32 + lrow) * K + c_sw * 8;
  short* al = LA + ((size_t)w * 256 + l) * 8;
  short* bl = LB + ((size_t)w * 256 + l) * 8;

  __syncthreads();  // protect LDS from previous task's readers
  for (int kc = 0; kc < K; kc += 64) {
    if (kc) __syncthreads();
    #pragma unroll
    for (int i = 0; i < 4; ++i) {
      gload_lds16(ag + kc + (size_t)i * 8 * K, al + i * 512);
      gload_lds16(bg + kc + (size_t)i * 8 * K, bl + i * 512);
    }
    __syncthreads();
    #pragma unroll
    for (int ks = 0; ks < 64; ks += 32) {
      int cb = (ks >> 3) + quad;
      short8 af[4], bfr[4];
      #pragma unroll
      for (int mt = 0; mt < 4; ++mt) {
        int mr = mw + mt * 16 + l16;
        af[mt] = *(const short8*)&LA[mr * 64 + ((cb ^ (mr & 7)) * 8)];
      }
      #pragma unroll
      for (int nt = 0; nt < 4; ++nt) {
        int nr = nw + nt * 16 + l16;
        bfr[nt] = *(const short8*)&LB[nr * 64 + ((cb ^ (nr & 7)) * 8)];
      }
      #pragma unroll
      for (int mt = 0; mt < 4; ++mt)
        #pragma unroll
        for (int nt = 0; nt < 4; ++nt)
          acc[mt][nt] = __builtin_amdgcn_mfma_f32_16x16x32_bf16(af[mt], bfr[nt], acc[mt][nt], 0, 0, 0);
    }
  }
  #pragma unroll
  for (int nt = 0; nt < 4; ++nt) {
    int gcol = n0 + nw + nt * 16 + l16;
    float bias = P.g3b[gcol];
    float s2 = 0.f;
    #pragma unroll
    for (int mt = 0; mt < 4; ++mt)
      #pragma unroll
      for (int r = 0; r < 4; ++r)
        s2 += fmaxf(acc[mt][nt][r] + bias, 0.f);
    s2 += __shfl_xor(s2, 16, 64);
    s2 += __shfl_xor(s2, 32, 64);
    if (quad == 0) atomicAdd(&P.out[b * 3072 + gcol], s2);
  }
}

// ---------------- the mega kernel: whole pipeline, grid.sync between stages ----------------
__global__ void __launch_bounds__(256) mega_kernel(MegaParams P) {
  __shared__ __align__(16) short LA[8192];   // 16 KB (conv/gemm64: [2][4096] dbuf view)
  __shared__ __align__(16) short LB[8192];   // 16 KB
  __shared__ float wsl[256];                 // 1 KB (gemm2)
  cg::grid_group grid = cg::this_grid();
  int bid = blockIdx.x, nb = gridDim.x, tid = threadIdx.x;

  for (int t = bid; t < 10433; t += nb) prep_task(P, t, tid, LA, LB);
  grid.sync();
  for (int t = bid; t < 192; t += nb)
    conv_task<6, true>(P.p1, P.w2r, P.b2, P.p2, (const bf16*)P.zbuf, 32, 48, 128, 128,
                       t & 1, t >> 1, tid, LA, LB);
  grid.sync();
  for (int t = bid; t < 96; t += nb)
    conv_task<7, true>(P.p2, P.w3r, P.b3, P.p3, (const bf16*)P.zbuf, 16, 24, 256, 256,
                       t & 3, t >> 2, tid, LA, LB);
  grid.sync();
  for (int t = bid; t < 48; t += nb)
    conv_task<8, false>(P.p3, P.w4r, P.b4, P.Fe, (const bf16*)P.zbuf, 8, 12, 512, 576,
                        t & 7, t >> 3, tid, LA, LB);
  grid.sync();
  for (int t = bid; t < 84; t += nb)
    gemm64_task(P.Fe, P.wuv, P.uvws, 576, 768, t % 12, t / 12, tid, LA, LB);
  grid.sync();
  for (int t = bid; t < 576; t += nb) gemm2_task(P, t, tid, LA, LB, wsl);
  grid.sync();
  for (int t = bid; t < 6912; t += nb) gemm3_task(P, t, tid, LA, LB);
}

extern "C" void kernel_launch(void* const* d_in, const int* in_sizes, int n_in,
                              void* d_out, int out_size, void* d_ws, size_t ws_size,
                              hipStream_t stream) {
  char* wsp = (char*)d_ws;
  size_t off = 0;
  auto alloc = [&](size_t bytes) {
    char* p = wsp + off;
    off += (bytes + 255) & ~(size_t)255;
    return (void*)p;
  };
  MegaParams P;
  P.x   = (const float*)d_in[0];
  P.sen = (const float*)d_in[1];
  P.w1  = (const float*)d_in[2];
  P.b1  = (const float*)d_in[3];
  P.w2  = (const float*)d_in[4];
  P.b2  = (const float*)d_in[5];
  P.w3  = (const float*)d_in[6];
  P.b3  = (const float*)d_in[7];
  P.w4  = (const float*)d_in[8];
  P.b4  = (const float*)d_in[9];
  P.g1w = (const float*)d_in[10];
  P.g1b = (const float*)d_in[11];
  P.g2w = (const float*)d_in[12];
  P.g2b = (const float*)d_in[13];
  P.g3w = (const float*)d_in[14];
  P.g3b = (const float*)d_in[15];
  P.out = (float*)d_out;
  P.p1   = (bf16*)alloc((size_t)6144 * 64 * 2);
  P.p2   = (bf16*)alloc((size_t)1536 * 128 * 2);
  P.p3   = (bf16*)alloc((size_t)384 * 256 * 2);
  P.Fe   = (bf16*)alloc((size_t)448 * 576 * 2);
  P.wuv  = (bf16*)alloc((size_t)768 * 576 * 2);
  P.uvws = (float*)alloc((size_t)448 * 768 * 4);
  P.w2r  = (bf16*)alloc((size_t)128 * 576 * 2);
  P.w3r  = (bf16*)alloc((size_t)256 * 1152 * 2);
  P.w4r  = (bf16*)alloc((size_t)512 * 2304 * 2);
  P.w2t  = (bf16*)alloc((size_t)256 * 256 * 2);
  P.w3t  = (bf16*)alloc((size_t)3072 * 256 * 2);
  P.h2   = (bf16*)alloc((size_t)4 * 9216 * 256 * 2);
  P.zbuf = (float*)alloc((size_t)256);

  // size the cooperative grid to guaranteed co-residency (cap at 3 blocks/CU to
  // keep gemm3's proven occupancy regime; grid stays a multiple of 8 for XCD swizzle)
  int maxB = 0;
  (void)hipOccupancyMaxActiveBlocksPerMultiprocessor(&maxB, mega_kernel, 256, 0);
  if (maxB < 1) maxB = 1;
  if (maxB > 3) maxB = 3;
  int nb = maxB * 256;

  void* kargs[] = { (void*)&P };
  (void)hipLaunchCooperativeKernel((void*)mega_kernel, dim3(nb), dim3(256), kargs, 0, stream);
}

// Round 11
// 242.167 us; speedup vs baseline: 2.1287x; 2.1287x over previous
//
#include <hip/hip_runtime.h>
#include <hip/hip_bf16.h>

using bf16 = __hip_bfloat16;
typedef __attribute__((ext_vector_type(8))) short short8;
typedef __attribute__((ext_vector_type(4))) float f32x4;

static __device__ __forceinline__ bf16 f2b(float x) { return __float2bfloat16(x); }
static __device__ __forceinline__ float b2f(bf16 x) { return __bfloat162float(x); }
static __device__ __forceinline__ short fb(float x) {
  bf16 h = __float2bfloat16(fmaxf(x, 0.f));
  return *(short*)&h;
}

// async global->LDS, 16B per lane. Global src address is PER-LANE; LDS dest = uniform base + lane*16.
static __device__ __forceinline__ void gload_lds16(const void* g, void* l) {
  auto gp = (const __attribute__((address_space(1))) unsigned int*)g;
  auto lp = (__attribute__((address_space(3))) unsigned int*)l;
  __builtin_amdgcn_global_load_lds(gp, lp, 16, 0, 0);
}

// ---------------- merged prep: x->NHWC8 + weight reorders + wuv + transposes + zeroing ----------------
// block ranges: [0,768) x8 build ; [768, 8865) scalar prep ; [8865, 9697) transposes
__global__ void prep_all_kernel(const float* __restrict__ x, const float* __restrict__ w1,
                                bf16* __restrict__ x8, bf16* __restrict__ w1r,
                                const float* __restrict__ w2, const float* __restrict__ w3,
                                const float* __restrict__ w4, const float* __restrict__ g1w,
                                const float* __restrict__ sen, float* __restrict__ outz,
                                bf16* __restrict__ w2r, bf16* __restrict__ w3r,
                                bf16* __restrict__ w4r, bf16* __restrict__ wuv,
                                bf16* __restrict__ Fe, float* __restrict__ zb,
                                const float* __restrict__ g2w, const float* __restrict__ g3w,
                                bf16* __restrict__ w2t, bf16* __restrict__ w3t) {
  __shared__ bf16 tt[32][33];
  int bid = blockIdx.x;
  int tid = threadIdx.x;
  if (bid < 768) {
    // ---- x (NCHW f32) -> x8 (NHWC, C padded 3->8, bf16) ----
    int i = bid * 256 + tid;           // < 196608
    int c = i & 7, pix = i >> 3;       // pix = (b*64+y)*96+x, 24576 total
    int b = pix / 6144, rem = pix - b * 6144;
    float val = (c < 3) ? x[(size_t)(b * 3 + c) * 6144 + rem] : 0.f;
    x8[i] = f2b(val);
  } else if (bid < 8865) {
    // ---- scalar prep ranges ----
    const int SW1 = 8192, S1 = SW1 + 73728, S2 = S1 + 294912, S3 = S2 + 1179648,
              S4 = S3 + 442368, S5 = S4 + 12288, S6 = S5 + 24576, S7 = S6 + 36864,
              S8 = S7 + 64;
    int i = (bid - 768) * 256 + tid;
    if (i < SW1) {  // w1r[64][128]: tap*8+c, taps>=9 or c>=3 zero
      int oc = i >> 7, r = i & 127, tap = r >> 3, c = r & 7;
      float val = (tap < 9 && c < 3) ? w1[(size_t)(oc * 3 + c) * 9 + tap] : 0.f;
      w1r[i] = f2b(val);
    } else if (i < S1) {  // w2r: OC=128 IC=64, [oc][tap*IC+ic]
      int j = i - SW1, K = 576, IC = 64;
      int oc = j / K, r = j - oc * K, tap = r / IC, ic = r - tap * IC;
      w2r[j] = f2b(w2[((size_t)oc * IC + ic) * 9 + tap]);
    } else if (i < S2) {  // w3r
      int j = i - S1, K = 1152, IC = 128;
      int oc = j / K, r = j - oc * K, tap = r / IC, ic = r - tap * IC;
      w3r[j] = f2b(w3[((size_t)oc * IC + ic) * 9 + tap]);
    } else if (i < S3) {  // w4r
      int j = i - S2, K = 2304, IC = 256;
      int oc = j / K, r = j - oc * K, tap = r / IC, ic = r - tap * IC;
      w4r[j] = f2b(w4[((size_t)oc * IC + ic) * 9 + tap]);
    } else if (i < S4) {  // wuv[768][576]: [A^T ; Bm^T ; Cm^T]
      int j = i - S3;
      int n = j / 576, c = j - n * 576;
      float val = 0.f;
      if (n < 256)      { if (c < 514) val = g1w[(size_t)c * 256 + n]; }
      else if (n < 512) { if (c < 514) val = g1w[(size_t)(514 + c) * 256 + (n - 256)]; }
      else              { if (c < 384) val = g1w[(size_t)(1028 + c) * 256 + (n - 512)]; }
      wuv[j] = f2b(val);
    } else if (i < S5) {  // zero output accumulator (d_out)
      outz[i - S4] = 0.f;
    } else if (i < S6) {  // Fe rows 0..383, cols 512..575
      int j = i - S5;
      int r = j >> 6, cc = j & 63;
      int p = r % 96;
      float val = 0.f;
      if (cc == 0) val = -1.0f + 2.0f * (float)(p / 8) / 11.0f;
      else if (cc == 1) val = -1.0f + 2.0f * (float)(p % 8) / 7.0f;
      Fe[(size_t)r * 576 + 512 + cc] = f2b(val);
    } else if (i < S7) {  // Fe rows 384..447: sen rows
      int j = i - S6;
      int r = j / 576, c = j - r * 576;
      float val = (r < 4 && c < 384) ? sen[r * 384 + c] : 0.f;
      Fe[(size_t)(384 + r) * 576 + c] = f2b(val);
    } else if (i < S8) {
      zb[i - S7] = 0.f;
    }
  } else {
    // ---- transposes: g2w(256x256)->w2t, g3w(256x3072)->w3t ----
    int b2 = bid - 8865;
    const float* in;
    bf16* out;
    int R = 256, C, c0, r0;
    if (b2 < 64) { in = g2w; out = w2t; C = 256; c0 = (b2 & 7) * 32; r0 = (b2 >> 3) * 32; }
    else { b2 -= 64; in = g3w; out = w3t; C = 3072; c0 = (b2 % 96) * 32; r0 = (b2 / 96) * 32; }
    int xq = tid & 31, yq = tid >> 5;
    for (int yy = yq; yy < 32; yy += 8) {
      int r = r0 + yy, c = c0 + xq;
      if (r < R && c < C) tt[yy][xq] = f2b(in[(size_t)r * C + c]);
    }
    __syncthreads();
    for (int yy = yq; yy < 32; yy += 8) {
      int c = c0 + yy, r = r0 + xq;
      if (r < R && c < C) out[(size_t)c * R + r] = tt[xq][yy];
    }
  }
}

// ---------------- conv GEMM: implicit im2col + fused pool, double-buffered K-loop ----------------
// K = TAPS<<CBITS; taps >= 9 (padding taps, TAPS=16 case) read the zero buffer.
template <int CBITS, bool POOL, int TAPS = 9>
__launch_bounds__(256)
__global__ void gemm_conv_kernel(const bf16* __restrict__ pin, const bf16* __restrict__ Wt,
                                 const float* __restrict__ bias, bf16* __restrict__ outb,
                                 const bf16* __restrict__ zbuf,
                                 int Hi, int Wi, int N, int ldout) {
  const int C = 1 << CBITS;
  const int K = TAPS << CBITS;
  int m0 = blockIdx.y * 64, n0 = blockIdx.x * 64;
  __shared__ __align__(16) short A_lds[2][64 * 64];
  __shared__ __align__(16) short B_lds[2][64 * 64];
  int tid = threadIdx.x, w = tid >> 6, l = tid & 63;
  int quad = l >> 4, l16 = l & 15;
  f32x4 acc[4];
  #pragma unroll
  for (int nt = 0; nt < 4; ++nt)
    #pragma unroll
    for (int e = 0; e < 4; ++e) acc[nt][e] = 0.f;

  int lrow = l >> 3;
  int c_sw = (l & 7) ^ lrow;
  int ybase[2], xbase[2], bidx[2];
  #pragma unroll
  for (int i = 0; i < 2; ++i) {
    int row = m0 + w * 16 + i * 8 + lrow;
    if (POOL) {
      int pg = row >> 2, sub = row & 3;
      int Wh = Wi >> 1, HW2 = (Hi >> 1) * Wh;
      int b = pg / HW2, rem = pg - b * HW2;
      int py = rem / Wh, px = rem - py * Wh;
      bidx[i] = b; ybase[i] = 2 * py + (sub >> 1); xbase[i] = 2 * px + (sub & 1);
    } else {
      int HW = Hi * Wi;
      int b = row / HW, pix = row - b * HW;
      int yy = pix / Wi;
      bidx[i] = b; ybase[i] = yy; xbase[i] = pix - yy * Wi;
    }
  }
  const bf16* bg = Wt + (size_t)(n0 + w * 16 + lrow) * K + c_sw * 8;

  auto stage = [&](int kc, int buf) {
    int colt = kc + c_sw * 8;
    int tap = colt >> CBITS, cc = colt & (C - 1);
    int ty = tap / 3, tx = tap - 3 * ty;
    short* al = &A_lds[buf][((size_t)w * 128 + l) * 8];
    short* bl = &B_lds[buf][((size_t)w * 128 + l) * 8];
    #pragma unroll
    for (int i = 0; i < 2; ++i) {
      int yy = ybase[i] + ty - 1, xx = xbase[i] + tx - 1;
      bool ok = (tap < 9) && (yy >= 0) && (yy < Hi) && (xx >= 0) && (xx < Wi);
      const bf16* asrc = ok
          ? pin + ((((size_t)(bidx[i] * Hi + yy)) * Wi + xx) << CBITS) + cc
          : zbuf;
      gload_lds16(asrc, al + i * 512);
      gload_lds16(bg + kc + (size_t)i * 8 * K, bl + i * 512);
    }
  };

  stage(0, 0);
  const int NK = K >> 6;
  for (int ik = 0; ik < NK; ++ik) {
    int buf = ik & 1;
    __syncthreads();
    if (ik + 1 < NK) stage((ik + 1) * 64, buf ^ 1);
    #pragma unroll
    for (int ks = 0; ks < 64; ks += 32) {
      int cb = (ks >> 3) + quad;
      int mr = w * 16 + l16;
      short8 af = *(const short8*)&A_lds[buf][mr * 64 + ((cb ^ (mr & 7)) * 8)];
      #pragma unroll
      for (int nt = 0; nt < 4; ++nt) {
        int nr = nt * 16 + l16;
        short8 bf2 = *(const short8*)&B_lds[buf][nr * 64 + ((cb ^ (nr & 7)) * 8)];
        acc[nt] = __builtin_amdgcn_mfma_f32_16x16x32_bf16(af, bf2, acc[nt], 0, 0, 0);
      }
    }
  }
  if (POOL) {
    int pg = (m0 + w * 16 + quad * 4) >> 2;
    #pragma unroll
    for (int nt = 0; nt < 4; ++nt) {
      int gcol = n0 + nt * 16 + l16;
      float bv = bias[gcol];
      float m = fmaxf(fmaxf(acc[nt][0], acc[nt][1]), fmaxf(acc[nt][2], acc[nt][3]));
      outb[(size_t)pg * N + gcol] = f2b(fmaxf(m + bv, 0.f));
    }
  } else {
    #pragma unroll
    for (int nt = 0; nt < 4; ++nt) {
      int gcol = n0 + nt * 16 + l16;
      float bv = bias[gcol];
      #pragma unroll
      for (int r = 0; r < 4; ++r) {
        int grow = m0 + w * 16 + quad * 4 + r;
        outb[(size_t)grow * ldout + gcol] = f2b(fmaxf(acc[nt][r] + bv, 0.f));
      }
    }
  }
}

// ---------------- 64x64-tile GEMM, glds staging, double-buffered (uv head GEMM) ----------------
__launch_bounds__(256)
__global__ void gemm64_kernel(const bf16* __restrict__ A, const bf16* __restrict__ Wt,
                              float* __restrict__ outf, int K, int ldout) {
  int m0 = blockIdx.y * 64, n0 = blockIdx.x * 64;
  __shared__ __align__(16) short A_lds[2][64 * 64];
  __shared__ __align__(16) short B_lds[2][64 * 64];
  int tid = threadIdx.x, w = tid >> 6, l = tid & 63;
  int quad = l >> 4, l16 = l & 15;
  f32x4 acc[4];
  #pragma unroll
  for (int nt = 0; nt < 4; ++nt)
    #pragma unroll
    for (int e = 0; e < 4; ++e) acc[nt][e] = 0.f;

  int lrow = l >> 3;
  int c_sw = (l & 7) ^ lrow;
  const bf16* ag = A + (size_t)(m0 + w * 16 + lrow) * K + c_sw * 8;
  const bf16* bg = Wt + (size_t)(n0 + w * 16 + lrow) * K + c_sw * 8;

  auto stage = [&](int kc, int buf) {
    short* al = &A_lds[buf][((size_t)w * 128 + l) * 8];
    short* bl = &B_lds[buf][((size_t)w * 128 + l) * 8];
    #pragma unroll
    for (int i = 0; i < 2; ++i) {
      gload_lds16(ag + kc + (size_t)i * 8 * K, al + i * 512);
      gload_lds16(bg + kc + (size_t)i * 8 * K, bl + i * 512);
    }
  };

  stage(0, 0);
  const int NK = K >> 6;
  for (int ik = 0; ik < NK; ++ik) {
    int buf = ik & 1;
    __syncthreads();
    if (ik + 1 < NK) stage((ik + 1) * 64, buf ^ 1);
    #pragma unroll
    for (int ks = 0; ks < 64; ks += 32) {
      int cb = (ks >> 3) + quad;
      int mr = w * 16 + l16;
      short8 af = *(const short8*)&A_lds[buf][mr * 64 + ((cb ^ (mr & 7)) * 8)];
      #pragma unroll
      for (int nt = 0; nt < 4; ++nt) {
        int nr = nt * 16 + l16;
        short8 bf2 = *(const short8*)&B_lds[buf][nr * 64 + ((cb ^ (nr & 7)) * 8)];
        acc[nt] = __builtin_amdgcn_mfma_f32_16x16x32_bf16(af, bf2, acc[nt], 0, 0, 0);
      }
    }
  }
  #pragma unroll
  for (int nt = 0; nt < 4; ++nt) {
    int gcol = n0 + nt * 16 + l16;
    #pragma unroll
    for (int r = 0; r < 4; ++r) {
      int grow = m0 + w * 16 + quad * 4 + r;
      outf[(size_t)grow * ldout + gcol] = acc[nt][r];
    }
  }
}

// ---------------- GEMM2: h2 = relu(h1 @ W2 + b2); h1 formed on the fly ----------------
__launch_bounds__(256)
__global__ void gemm2_kernel(const float* __restrict__ uvws, const float* __restrict__ g1b,
                             const bf16* __restrict__ w2t, const float* __restrict__ g2b,
                             bf16* __restrict__ h2) {
  int b = blockIdx.z;
  int m0 = blockIdx.y * 128;
  int n0 = blockIdx.x * 128;
  __shared__ __align__(16) short A_lds[128 * 64];
  __shared__ __align__(16) short B_lds[128 * 64];
  __shared__ __align__(16) float wsl[256];
  int tid = threadIdx.x, w = tid >> 6, l = tid & 63;
  int quad = l >> 4, l16 = l & 15;
  int mw = (w >> 1) * 64, nw = (w & 1) * 64;
  f32x4 acc[4][4];
  #pragma unroll
  for (int i = 0; i < 4; ++i)
    #pragma unroll
    for (int j = 0; j < 4; ++j)
      #pragma unroll
      for (int e = 0; e < 4; ++e) acc[i][j][e] = 0.f;

  wsl[tid] = uvws[(size_t)(384 + b) * 768 + 512 + tid] + g1b[tid];

  int lrow = l >> 3;
  int c_sw = (l & 7) ^ lrow;
  const bf16* bg = w2t + (size_t)(n0 + w * 32 + lrow) * 256 + c_sw * 8;
  short* bl = B_lds + ((size_t)w * 256 + l) * 8;

  int row = tid >> 1, ks0 = (tid & 1) * 32;
  int m = m0 + row;
  int i_idx = m / 96, j_idx = m - i_idx * 96;
  const float* up = uvws + (size_t)(b * 96 + j_idx) * 768 + ks0;
  const float* vp = uvws + (size_t)(b * 96 + i_idx) * 768 + 256 + ks0;
  __syncthreads();

  for (int kc = 0; kc < 256; kc += 64) {
    if (kc) __syncthreads();
    #pragma unroll
    for (int i = 0; i < 4; ++i)
      gload_lds16(bg + kc + (size_t)i * 8 * 256, bl + i * 512);
    {
      const float4* u4 = (const float4*)(up + kc);
      const float4* v4 = (const float4*)(vp + kc);
      const float4* w4 = (const float4*)&wsl[kc + ks0];
      #pragma unroll
      for (int ch = 0; ch < 4; ++ch) {
        short8 pack;
        #pragma unroll
        for (int q = 0; q < 2; ++q) {
          float4 uu = u4[ch * 2 + q], vv = v4[ch * 2 + q], ww = w4[ch * 2 + q];
          pack[q * 4 + 0] = fb(uu.x + vv.x + ww.x);
          pack[q * 4 + 1] = fb(uu.y + vv.y + ww.y);
          pack[q * 4 + 2] = fb(uu.z + vv.z + ww.z);
          pack[q * 4 + 3] = fb(uu.w + vv.w + ww.w);
        }
        int lc = (ks0 >> 3) + ch;
        *(short8*)&A_lds[row * 64 + ((lc ^ (row & 7)) * 8)] = pack;
      }
    }
    __syncthreads();
    #pragma unroll
    for (int ks = 0; ks < 64; ks += 32) {
      int cb = (ks >> 3) + quad;
      short8 af[4], bfr[4];
      #pragma unroll
      for (int mt = 0; mt < 4; ++mt) {
        int mr = mw + mt * 16 + l16;
        af[mt] = *(const short8*)&A_lds[mr * 64 + ((cb ^ (mr & 7)) * 8)];
      }
      #pragma unroll
      for (int nt = 0; nt < 4; ++nt) {
        int nr = nw + nt * 16 + l16;
        bfr[nt] = *(const short8*)&B_lds[nr * 64 + ((cb ^ (nr & 7)) * 8)];
      }
      #pragma unroll
      for (int mt = 0; mt < 4; ++mt)
        #pragma unroll
        for (int nt = 0; nt < 4; ++nt)
          acc[mt][nt] = __builtin_amdgcn_mfma_f32_16x16x32_bf16(af[mt], bfr[nt], acc[mt][nt], 0, 0, 0);
    }
  }
  bf16* h2b = h2 + (size_t)b * 9216 * 256;
  #pragma unroll
  for (int nt = 0; nt < 4; ++nt) {
    int gcol = n0 + nw + nt * 16 + l16;
    float bias = g2b[gcol];
    #pragma unroll
    for (int mt = 0; mt < 4; ++mt) {
      #pragma unroll
      for (int r = 0; r < 4; ++r) {
        int grow = m0 + mw + mt * 16 + quad * 4 + r;
        h2b[(size_t)grow * 256 + gcol] = f2b(fmaxf(acc[mt][nt][r] + bias, 0.f));
      }
    }
  }
}

// ---------------- GEMM3 + relu + pair-sum, glds staging, XCD-swizzled grid ----------------
__launch_bounds__(256)
__global__ void gemm3_kernel(const bf16* __restrict__ h2, const bf16* __restrict__ w3t,
                             const float* __restrict__ g3b, float* __restrict__ phi) {
  int g = blockIdx.x;
  int x = g & 7, s = g >> 3;
  int grp = s / 24;
  int nIdx = s - grp * 24;
  int mb = grp * 8 + x;
  int b = mb / 72;
  int m0 = (mb - b * 72) * 128;
  int n0 = nIdx * 128;
  __shared__ __align__(16) short A_lds[128 * 64];
  __shared__ __align__(16) short B_lds[128 * 64];
  int tid = threadIdx.x, w = tid >> 6, l = tid & 63;
  int quad = l >> 4, l16 = l & 15;
  int mw = (w >> 1) * 64, nw = (w & 1) * 64;
  f32x4 acc[4][4];
  #pragma unroll
  for (int i = 0; i < 4; ++i)
    #pragma unroll
    for (int j = 0; j < 4; ++j)
      #pragma unroll
      for (int e = 0; e < 4; ++e) acc[i][j][e] = 0.f;

  const int K = 256;
  int lrow = l >> 3;
  int c_sw = (l & 7) ^ lrow;
  const bf16* ag = h2 + (size_t)(b * 9216 + m0 + w * 32 + lrow) * K + c_sw * 8;
  const bf16* bg = w3t + (size_t)(n0 + w * 32 + lrow) * K + c_sw * 8;
  short* al = A_lds + ((size_t)w * 256 + l) * 8;
  short* bl = B_lds + ((size_t)w * 256 + l) * 8;

  for (int kc = 0; kc < K; kc += 64) {
    if (kc) __syncthreads();
    #pragma unroll
    for (int i = 0; i < 4; ++i) {
      gload_lds16(ag + kc + (size_t)i * 8 * K, al + i * 512);
      gload_lds16(bg + kc + (size_t)i * 8 * K, bl + i * 512);
    }
    __syncthreads();
    #pragma unroll
    for (int ks = 0; ks < 64; ks += 32) {
      int cb = (ks >> 3) + quad;
      short8 af[4], bfr[4];
      #pragma unroll
      for (int mt = 0; mt < 4; ++mt) {
        int mr = mw + mt * 16 + l16;
        af[mt] = *(const short8*)&A_lds[mr * 64 + ((cb ^ (mr & 7)) * 8)];
      }
      #pragma unroll
      for (int nt = 0; nt < 4; ++nt) {
        int nr = nw + nt * 16 + l16;
        bfr[nt] = *(const short8*)&B_lds[nr * 64 + ((cb ^ (nr & 7)) * 8)];
      }
      #pragma unroll
      for (int mt = 0; mt < 4; ++mt)
        #pragma unroll
        for (int nt = 0; nt < 4; ++nt)
          acc[mt][nt] = __builtin_amdgcn_mfma_f32_16x16x32_bf16(af[mt], bfr[nt], acc[mt][nt], 0, 0, 0);
    }
  }
  #pragma unroll
  for (int nt = 0; nt < 4; ++nt) {
    int gcol = n0 + nw + nt * 16 + l16;
    float bias = g3b[gcol];
    float s2 = 0.f;
    #pragma unroll
    for (int mt = 0; mt < 4; ++mt)
      #pragma unroll
      for (int r = 0; r < 4; ++r)
        s2 += fmaxf(acc[mt][nt][r] + bias, 0.f);
    s2 += __shfl_xor(s2, 16, 64);
    s2 += __shfl_xor(s2, 32, 64);
    if (quad == 0) atomicAdd(&phi[b * 3072 + gcol], s2);
  }
}

extern "C" void kernel_launch(void* const* d_in, const int* in_sizes, int n_in,
                              void* d_out, int out_size, void* d_ws, size_t ws_size,
                              hipStream_t stream) {
  const float* x   = (const float*)d_in[0];
  const float* sen = (const float*)d_in[1];
  const float* w1  = (const float*)d_in[2];
  const float* b1  = (const float*)d_in[3];
  const float* w2  = (const float*)d_in[4];
  const float* b2  = (const float*)d_in[5];
  const float* w3  = (const float*)d_in[6];
  const float* b3  = (const float*)d_in[7];
  const float* w4  = (const float*)d_in[8];
  const float* b4  = (const float*)d_in[9];
  const float* g1w = (const float*)d_in[10];
  const float* g1b = (const float*)d_in[11];
  const float* g2w = (const float*)d_in[12];
  const float* g2b = (const float*)d_in[13];
  const float* g3w = (const float*)d_in[14];
  const float* g3b = (const float*)d_in[15];
  float* out = (float*)d_out;

  char* wsp = (char*)d_ws;
  size_t off = 0;
  auto alloc = [&](size_t bytes) {
    char* p = wsp + off;
    off += (bytes + 255) & ~(size_t)255;
    return (void*)p;
  };
  bf16* x8   = (bf16*)alloc((size_t)24576 * 8 * 2);        // NHWC8 input copy
  bf16* w1r  = (bf16*)alloc((size_t)64 * 128 * 2);
  bf16* p1   = (bf16*)alloc((size_t)6144 * 64 * 2);
  bf16* p2   = (bf16*)alloc((size_t)1536 * 128 * 2);
  bf16* p3   = (bf16*)alloc((size_t)384 * 256 * 2);
  bf16* Fe   = (bf16*)alloc((size_t)448 * 576 * 2);
  bf16* wuv  = (bf16*)alloc((size_t)768 * 576 * 2);
  float* uvws = (float*)alloc((size_t)448 * 768 * 4);
  bf16* w2r  = (bf16*)alloc((size_t)128 * 576 * 2);
  bf16* w3r  = (bf16*)alloc((size_t)256 * 1152 * 2);
  bf16* w4r  = (bf16*)alloc((size_t)512 * 2304 * 2);
  bf16* w2t  = (bf16*)alloc((size_t)256 * 256 * 2);
  bf16* w3t  = (bf16*)alloc((size_t)3072 * 256 * 2);
  bf16* h2   = (bf16*)alloc((size_t)4 * 9216 * 256 * 2);
  float* zbuf = (float*)alloc((size_t)256);

  // prep (x8 + reorders + transposes + d_out zero), input-only deps
  prep_all_kernel<<<dim3(9697), 256, 0, stream>>>(x, w1, x8, w1r, w2, w3, w4, g1w, sen, out,
                                                  w2r, w3r, w4r, wuv, Fe, zbuf, g2w, g3w, w2t, w3t);

  // encoder: all four convs as implicit-im2col MFMA GEMMs with fused pooling (double-buffered)
  gemm_conv_kernel<3, true, 16><<<dim3(1, 384), 256, 0, stream>>>(x8, w1r, b1, p1, (const bf16*)zbuf, 64, 96, 64, 64);
  gemm_conv_kernel<6, true><<<dim3(2, 96), 256, 0, stream>>>(p1, w2r, b2, p2, (const bf16*)zbuf, 32, 48, 128, 128);
  gemm_conv_kernel<7, true><<<dim3(4, 24), 256, 0, stream>>>(p2, w3r, b3, p3, (const bf16*)zbuf, 16, 24, 256, 256);
  gemm_conv_kernel<8, false><<<dim3(8, 6), 256, 0, stream>>>(p3, w4r, b4, Fe, (const bf16*)zbuf, 8, 12, 512, 576);

  // head: u,v,ws GEMM (double-buffered), gemm2, gemm3
  gemm64_kernel<<<dim3(12, 7), 256, 0, stream>>>(Fe, wuv, uvws, 576, 768);
  gemm2_kernel<<<dim3(2, 72, 4), 256, 0, stream>>>(uvws, g1b, w2t, g2b, h2);
  gemm3_kernel<<<dim3(6912), 256, 0, stream>>>(h2, w3t, g3b, out);
}

// Round 12
// 240.397 us; speedup vs baseline: 2.1444x; 1.0074x over previous
//
#include <hip/hip_runtime.h>
#include <hip/hip_bf16.h>

using bf16 = __hip_bfloat16;
typedef __attribute__((ext_vector_type(8))) short short8;
typedef __attribute__((ext_vector_type(4))) float f32x4;

static __device__ __forceinline__ bf16 f2b(float x) { return __float2bfloat16(x); }
static __device__ __forceinline__ float b2f(bf16 x) { return __bfloat162float(x); }
static __device__ __forceinline__ short fb(float x) {
  bf16 h = __float2bfloat16(fmaxf(x, 0.f));
  return *(short*)&h;
}

// async global->LDS, 16B per lane. Global src address is PER-LANE; LDS dest = uniform base + lane*16.
static __device__ __forceinline__ void gload_lds16(const void* g, void* l) {
  auto gp = (const __attribute__((address_space(1))) unsigned int*)g;
  auto lp = (__attribute__((address_space(3))) unsigned int*)l;
  __builtin_amdgcn_global_load_lds(gp, lp, 16, 0, 0);
}

// ---------------- merged prep: conv1pool + weight reorders + wuv + transposes + zeroing ----------------
// block ranges: [0,1536) conv1+pool ; [1536, 9601) scalar prep ; [9601, 10433) transposes
__global__ void prep_all_kernel(const float* __restrict__ x, const float* __restrict__ w1,
                                const float* __restrict__ b1, bf16* __restrict__ p1,
                                const float* __restrict__ w2, const float* __restrict__ w3,
                                const float* __restrict__ w4, const float* __restrict__ g1w,
                                const float* __restrict__ sen, float* __restrict__ outz,
                                bf16* __restrict__ w2r, bf16* __restrict__ w3r,
                                bf16* __restrict__ w4r, bf16* __restrict__ wuv,
                                bf16* __restrict__ Fe, float* __restrict__ zb,
                                const float* __restrict__ g2w, const float* __restrict__ g3w,
                                bf16* __restrict__ w2t, bf16* __restrict__ w3t) {
  __shared__ float wl[27 * 64];
  __shared__ bf16 tt[32][33];
  int bid = blockIdx.x;
  int tid = threadIdx.x;
  if (bid < 1536) {
    // ---- conv1 + maxpool: NCHW f32 -> pooled NHWC bf16 [4][32][48][64] ----
    const int H = 64, W = 96, HW = H * W;
    for (int idx = tid; idx < 27 * 64; idx += 256) {
      int k = idx >> 6, oc_ = idx & 63;
      wl[idx] = w1[oc_ * 27 + k];
    }
    __syncthreads();
    int oc = tid & 63;
    int pp = bid * 4 + (tid >> 6);
    int b = pp / 1536, rem = pp - b * 1536;
    int yp = rem / 48, xp = rem - yp * 48;
    int y0 = 2 * yp - 1, x0 = 2 * xp - 1;
    float win[3][4][4];
    #pragma unroll
    for (int ic = 0; ic < 3; ++ic) {
      const float* xsrc = x + ((size_t)b * 3 + ic) * HW;
      #pragma unroll
      for (int dy = 0; dy < 4; ++dy) {
        int yy = y0 + dy;
        #pragma unroll
        for (int dx = 0; dx < 4; ++dx) {
          int xx = x0 + dx;
          win[ic][dy][dx] = (yy >= 0 && yy < H && xx >= 0 && xx < W) ? xsrc[yy * W + xx] : 0.f;
        }
      }
    }
    float cmax = -1e30f;
    #pragma unroll
    for (int sy = 0; sy < 2; ++sy)
      #pragma unroll
      for (int sx = 0; sx < 2; ++sx) {
        float acc = 0.f;
        #pragma unroll
        for (int ic = 0; ic < 3; ++ic)
          #pragma unroll
          for (int ky = 0; ky < 3; ++ky)
            #pragma unroll
            for (int kx = 0; kx < 3; ++kx)
              acc += win[ic][sy + ky][sx + kx] * wl[(ic * 9 + ky * 3 + kx) * 64 + oc];
        cmax = fmaxf(cmax, acc);
      }
    p1[(size_t)pp * 64 + oc] = f2b(fmaxf(cmax + b1[oc], 0.f));
  } else if (bid < 9601) {
    // ---- scalar prep ranges ----
    const int S1 = 73728, S2 = S1 + 294912, S3 = S2 + 1179648, S4 = S3 + 442368,
              S5 = S4 + 12288, S6 = S5 + 24576, S7 = S6 + 36864, S8 = S7 + 64;
    int i = (bid - 1536) * 256 + tid;
    if (i < S1) {  // w2r: OC=128 IC=64, [oc][tap*IC+ic]
      int j = i, K = 576, IC = 64;
      int oc = j / K, r = j - oc * K, tap = r / IC, ic = r - tap * IC;
      w2r[j] = f2b(w2[((size_t)oc * IC + ic) * 9 + tap]);
    } else if (i < S2) {  // w3r
      int j = i - S1, K = 1152, IC = 128;
      int oc = j / K, r = j - oc * K, tap = r / IC, ic = r - tap * IC;
      w3r[j] = f2b(w3[((size_t)oc * IC + ic) * 9 + tap]);
    } else if (i < S3) {  // w4r
      int j = i - S2, K = 2304, IC = 256;
      int oc = j / K, r = j - oc * K, tap = r / IC, ic = r - tap * IC;
      w4r[j] = f2b(w4[((size_t)oc * IC + ic) * 9 + tap]);
    } else if (i < S4) {  // wuv[768][576]: [A^T ; Bm^T ; Cm^T]
      int j = i - S3;
      int n = j / 576, c = j - n * 576;
      float val = 0.f;
      if (n < 256)      { if (c < 514) val = g1w[(size_t)c * 256 + n]; }
      else if (n < 512) { if (c < 514) val = g1w[(size_t)(514 + c) * 256 + (n - 256)]; }
      else              { if (c < 384) val = g1w[(size_t)(1028 + c) * 256 + (n - 512)]; }
      wuv[j] = f2b(val);
    } else if (i < S5) {  // zero output accumulator (d_out)
      outz[i - S4] = 0.f;
    } else if (i < S6) {  // Fe rows 0..383, cols 512..575
      int j = i - S5;
      int r = j >> 6, cc = j & 63;
      int p = r % 96;
      float val = 0.f;
      if (cc == 0) val = -1.0f + 2.0f * (float)(p / 8) / 11.0f;
      else if (cc == 1) val = -1.0f + 2.0f * (float)(p % 8) / 7.0f;
      Fe[(size_t)r * 576 + 512 + cc] = f2b(val);
    } else if (i < S7) {  // Fe rows 384..447: sen rows
      int j = i - S6;
      int r = j / 576, c = j - r * 576;
      float val = (r < 4 && c < 384) ? sen[r * 384 + c] : 0.f;
      Fe[(size_t)(384 + r) * 576 + c] = f2b(val);
    } else if (i < S8) {
      zb[i - S7] = 0.f;
    }
  } else {
    // ---- transposes: g2w(256x256)->w2t, g3w(256x3072)->w3t ----
    int b2 = bid - 9601;
    const float* in;
    bf16* out;
    int R = 256, C, c0, r0;
    if (b2 < 64) { in = g2w; out = w2t; C = 256; c0 = (b2 & 7) * 32; r0 = (b2 >> 3) * 32; }
    else { b2 -= 64; in = g3w; out = w3t; C = 3072; c0 = (b2 % 96) * 32; r0 = (b2 / 96) * 32; }
    int xq = tid & 31, yq = tid >> 5;
    for (int yy = yq; yy < 32; yy += 8) {
      int r = r0 + yy, c = c0 + xq;
      if (r < R && c < C) tt[yy][xq] = f2b(in[(size_t)r * C + c]);
    }
    __syncthreads();
    for (int yy = yq; yy < 32; yy += 8) {
      int c = c0 + yy, r = r0 + xq;
      if (r < R && c < C) out[(size_t)c * R + r] = tt[xq][yy];
    }
  }
}

// ---------------- conv GEMM: implicit im2col + fused pool, double-buffered K-loop ----------------
template <int CBITS, bool POOL>
__launch_bounds__(256)
__global__ void gemm_conv_kernel(const bf16* __restrict__ pin, const bf16* __restrict__ Wt,
                                 const float* __restrict__ bias, bf16* __restrict__ outb,
                                 const bf16* __restrict__ zbuf,
                                 int Hi, int Wi, int N, int ldout) {
  const int C = 1 << CBITS;
  const int K = 9 << CBITS;
  int m0 = blockIdx.y * 64, n0 = blockIdx.x * 64;
  __shared__ __align__(16) short A_lds[2][64 * 64];
  __shared__ __align__(16) short B_lds[2][64 * 64];
  int tid = threadIdx.x, w = tid >> 6, l = tid & 63;
  int quad = l >> 4, l16 = l & 15;
  f32x4 acc[4];
  #pragma unroll
  for (int nt = 0; nt < 4; ++nt)
    #pragma unroll
    for (int e = 0; e < 4; ++e) acc[nt][e] = 0.f;

  int lrow = l >> 3;
  int c_sw = (l & 7) ^ lrow;
  int ybase[2], xbase[2], bidx[2];
  #pragma unroll
  for (int i = 0; i < 2; ++i) {
    int row = m0 + w * 16 + i * 8 + lrow;
    if (POOL) {
      int pg = row >> 2, sub = row & 3;
      int Wh = Wi >> 1, HW2 = (Hi >> 1) * Wh;
      int b = pg / HW2, rem = pg - b * HW2;
      int py = rem / Wh, px = rem - py * Wh;
      bidx[i] = b; ybase[i] = 2 * py + (sub >> 1); xbase[i] = 2 * px + (sub & 1);
    } else {
      int HW = Hi * Wi;
      int b = row / HW, pix = row - b * HW;
      int yy = pix / Wi;
      bidx[i] = b; ybase[i] = yy; xbase[i] = pix - yy * Wi;
    }
  }
  const bf16* bg = Wt + (size_t)(n0 + w * 16 + lrow) * K + c_sw * 8;

  auto stage = [&](int kc, int buf) {
    int colt = kc + c_sw * 8;
    int tap = colt >> CBITS, cc = colt & (C - 1);
    int ty = tap / 3, tx = tap - 3 * ty;
    short* al = &A_lds[buf][((size_t)w * 128 + l) * 8];
    short* bl = &B_lds[buf][((size_t)w * 128 + l) * 8];
    #pragma unroll
    for (int i = 0; i < 2; ++i) {
      int yy = ybase[i] + ty - 1, xx = xbase[i] + tx - 1;
      const bf16* asrc = (yy >= 0 && yy < Hi && xx >= 0 && xx < Wi)
          ? pin + ((((size_t)(bidx[i] * Hi + yy)) * Wi + xx) << CBITS) + cc
          : zbuf;
      gload_lds16(asrc, al + i * 512);
      gload_lds16(bg + kc + (size_t)i * 8 * K, bl + i * 512);
    }
  };

  stage(0, 0);
  const int NK = K >> 6;
  for (int ik = 0; ik < NK; ++ik) {
    int buf = ik & 1;
    __syncthreads();
    if (ik + 1 < NK) stage((ik + 1) * 64, buf ^ 1);
    #pragma unroll
    for (int ks = 0; ks < 64; ks += 32) {
      int cb = (ks >> 3) + quad;
      int mr = w * 16 + l16;
      short8 af = *(const short8*)&A_lds[buf][mr * 64 + ((cb ^ (mr & 7)) * 8)];
      #pragma unroll
      for (int nt = 0; nt < 4; ++nt) {
        int nr = nt * 16 + l16;
        short8 bf2 = *(const short8*)&B_lds[buf][nr * 64 + ((cb ^ (nr & 7)) * 8)];
        acc[nt] = __builtin_amdgcn_mfma_f32_16x16x32_bf16(af, bf2, acc[nt], 0, 0, 0);
      }
    }
  }
  if (POOL) {
    int pg = (m0 + w * 16 + quad * 4) >> 2;
    #pragma unroll
    for (int nt = 0; nt < 4; ++nt) {
      int gcol = n0 + nt * 16 + l16;
      float bv = bias[gcol];
      float m = fmaxf(fmaxf(acc[nt][0], acc[nt][1]), fmaxf(acc[nt][2], acc[nt][3]));
      outb[(size_t)pg * N + gcol] = f2b(fmaxf(m + bv, 0.f));
    }
  } else {
    #pragma unroll
    for (int nt = 0; nt < 4; ++nt) {
      int gcol = n0 + nt * 16 + l16;
      float bv = bias[gcol];
      #pragma unroll
      for (int r = 0; r < 4; ++r) {
        int grow = m0 + w * 16 + quad * 4 + r;
        outb[(size_t)grow * ldout + gcol] = f2b(fmaxf(acc[nt][r] + bv, 0.f));
      }
    }
  }
}

// ---------------- 64x64-tile GEMM, glds staging, double-buffered (uv head GEMM) ----------------
__launch_bounds__(256)
__global__ void gemm64_kernel(const bf16* __restrict__ A, const bf16* __restrict__ Wt,
                              float* __restrict__ outf, int K, int ldout) {
  int m0 = blockIdx.y * 64, n0 = blockIdx.x * 64;
  __shared__ __align__(16) short A_lds[2][64 * 64];
  __shared__ __align__(16) short B_lds[2][64 * 64];
  int tid = threadIdx.x, w = tid >> 6, l = tid & 63;
  int quad = l >> 4, l16 = l & 15;
  f32x4 acc[4];
  #pragma unroll
  for (int nt = 0; nt < 4; ++nt)
    #pragma unroll
    for (int e = 0; e < 4; ++e) acc[nt][e] = 0.f;

  int lrow = l >> 3;
  int c_sw = (l & 7) ^ lrow;
  const bf16* ag = A + (size_t)(m0 + w * 16 + lrow) * K + c_sw * 8;
  const bf16* bg = Wt + (size_t)(n0 + w * 16 + lrow) * K + c_sw * 8;

  auto stage = [&](int kc, int buf) {
    short* al = &A_lds[buf][((size_t)w * 128 + l) * 8];
    short* bl = &B_lds[buf][((size_t)w * 128 + l) * 8];
    #pragma unroll
    for (int i = 0; i < 2; ++i) {
      gload_lds16(ag + kc + (size_t)i * 8 * K, al + i * 512);
      gload_lds16(bg + kc + (size_t)i * 8 * K, bl + i * 512);
    }
  };

  stage(0, 0);
  const int NK = K >> 6;
  for (int ik = 0; ik < NK; ++ik) {
    int buf = ik & 1;
    __syncthreads();
    if (ik + 1 < NK) stage((ik + 1) * 64, buf ^ 1);
    #pragma unroll
    for (int ks = 0; ks < 64; ks += 32) {
      int cb = (ks >> 3) + quad;
      int mr = w * 16 + l16;
      short8 af = *(const short8*)&A_lds[buf][mr * 64 + ((cb ^ (mr & 7)) * 8)];
      #pragma unroll
      for (int nt = 0; nt < 4; ++nt) {
        int nr = nt * 16 + l16;
        short8 bf2 = *(const short8*)&B_lds[buf][nr * 64 + ((cb ^ (nr & 7)) * 8)];
        acc[nt] = __builtin_amdgcn_mfma_f32_16x16x32_bf16(af, bf2, acc[nt], 0, 0, 0);
      }
    }
  }
  #pragma unroll
  for (int nt = 0; nt < 4; ++nt) {
    int gcol = n0 + nt * 16 + l16;
    #pragma unroll
    for (int r = 0; r < 4; ++r) {
      int grow = m0 + w * 16 + quad * 4 + r;
      outf[(size_t)grow * ldout + gcol] = acc[nt][r];
    }
  }
}

// ---------------- GEMM2: h2 = relu(h1 @ W2 + b2); h1 formed on the fly ----------------
__launch_bounds__(256)
__global__ void gemm2_kernel(const float* __restrict__ uvws, const float* __restrict__ g1b,
                             const bf16* __restrict__ w2t, const float* __restrict__ g2b,
                             bf16* __restrict__ h2) {
  int b = blockIdx.z;
  int m0 = blockIdx.y * 128;
  int n0 = blockIdx.x * 128;
  __shared__ __align__(16) short A_lds[128 * 64];
  __shared__ __align__(16) short B_lds[128 * 64];
  __shared__ __align__(16) float wsl[256];
  int tid = threadIdx.x, w = tid >> 6, l = tid & 63;
  int quad = l >> 4, l16 = l & 15;
  int mw = (w >> 1) * 64, nw = (w & 1) * 64;
  f32x4 acc[4][4];
  #pragma unroll
  for (int i = 0; i < 4; ++i)
    #pragma unroll
    for (int j = 0; j < 4; ++j)
      #pragma unroll
      for (int e = 0; e < 4; ++e) acc[i][j][e] = 0.f;

  wsl[tid] = uvws[(size_t)(384 + b) * 768 + 512 + tid] + g1b[tid];

  int lrow = l >> 3;
  int c_sw = (l & 7) ^ lrow;
  const bf16* bg = w2t + (size_t)(n0 + w * 32 + lrow) * 256 + c_sw * 8;
  short* bl = B_lds + ((size_t)w * 256 + l) * 8;

  int row = tid >> 1, ks0 = (tid & 1) * 32;
  int m = m0 + row;
  int i_idx = m / 96, j_idx = m - i_idx * 96;
  const float* up = uvws + (size_t)(b * 96 + j_idx) * 768 + ks0;
  const float* vp = uvws + (size_t)(b * 96 + i_idx) * 768 + 256 + ks0;
  __syncthreads();

  for (int kc = 0; kc < 256; kc += 64) {
    if (kc) __syncthreads();
    #pragma unroll
    for (int i = 0; i < 4; ++i)
      gload_lds16(bg + kc + (size_t)i * 8 * 256, bl + i * 512);
    {
      const float4* u4 = (const float4*)(up + kc);
      const float4* v4 = (const float4*)(vp + kc);
      const float4* w4 = (const float4*)&wsl[kc + ks0];
      #pragma unroll
      for (int ch = 0; ch < 4; ++ch) {
        short8 pack;
        #pragma unroll
        for (int q = 0; q < 2; ++q) {
          float4 uu = u4[ch * 2 + q], vv = v4[ch * 2 + q], ww = w4[ch * 2 + q];
          pack[q * 4 + 0] = fb(uu.x + vv.x + ww.x);
          pack[q * 4 + 1] = fb(uu.y + vv.y + ww.y);
          pack[q * 4 + 2] = fb(uu.z + vv.z + ww.z);
          pack[q * 4 + 3] = fb(uu.w + vv.w + ww.w);
        }
        int lc = (ks0 >> 3) + ch;
        *(short8*)&A_lds[row * 64 + ((lc ^ (row & 7)) * 8)] = pack;
      }
    }
    __syncthreads();
    #pragma unroll
    for (int ks = 0; ks < 64; ks += 32) {
      int cb = (ks >> 3) + quad;
      short8 af[4], bfr[4];
      #pragma unroll
      for (int mt = 0; mt < 4; ++mt) {
        int mr = mw + mt * 16 + l16;
        af[mt] = *(const short8*)&A_lds[mr * 64 + ((cb ^ (mr & 7)) * 8)];
      }
      #pragma unroll
      for (int nt = 0; nt < 4; ++nt) {
        int nr = nw + nt * 16 + l16;
        bfr[nt] = *(const short8*)&B_lds[nr * 64 + ((cb ^ (nr & 7)) * 8)];
      }
      #pragma unroll
      for (int mt = 0; mt < 4; ++mt)
        #pragma unroll
        for (int nt = 0; nt < 4; ++nt)
          acc[mt][nt] = __builtin_amdgcn_mfma_f32_16x16x32_bf16(af[mt], bfr[nt], acc[mt][nt], 0, 0, 0);
    }
  }
  bf16* h2b = h2 + (size_t)b * 9216 * 256;
  #pragma unroll
  for (int nt = 0; nt < 4; ++nt) {
    int gcol = n0 + nw + nt * 16 + l16;
    float bias = g2b[gcol];
    #pragma unroll
    for (int mt = 0; mt < 4; ++mt) {
      #pragma unroll
      for (int r = 0; r < 4; ++r) {
        int grow = m0 + mw + mt * 16 + quad * 4 + r;
        h2b[(size_t)grow * 256 + gcol] = f2b(fmaxf(acc[mt][nt][r] + bias, 0.f));
      }
    }
  }
}

// ---------------- GEMM3 + relu + pair-sum: 192x128 block, 96x64 waves, XCD-swizzled ----------------
// grid 4608 = 8(xcd) x 24(grp) x 24(n); mb = grp*8+xcd in [0,192), 48 m-tiles of 192 per batch.
__launch_bounds__(256, 3)
__global__ void gemm3_kernel(const bf16* __restrict__ h2, const bf16* __restrict__ w3t,
                             const float* __restrict__ g3b, float* __restrict__ phi) {
  int g = blockIdx.x;
  int x = g & 7, s = g >> 3;
  int grp = s / 24;
  int nIdx = s - grp * 24;
  int mb = grp * 8 + x;
  int b = mb / 48;
  int m0 = (mb - b * 48) * 192;
  int n0 = nIdx * 128;
  __shared__ __align__(16) short A_lds[192 * 64];  // 24.5 KB
  __shared__ __align__(16) short B_lds[128 * 64];  // 16 KB
  int tid = threadIdx.x, w = tid >> 6, l = tid & 63;
  int quad = l >> 4, l16 = l & 15;
  int mw = (w >> 1) * 96, nw = (w & 1) * 64;
  f32x4 acc[6][4];
  #pragma unroll
  for (int i = 0; i < 6; ++i)
    #pragma unroll
    for (int j = 0; j < 4; ++j)
      #pragma unroll
      for (int e = 0; e < 4; ++e) acc[i][j][e] = 0.f;

  const int K = 256;
  int lrow = l >> 3;
  int c_sw = (l & 7) ^ lrow;
  // A staging: wave w stages rows w*48 + i*8 + lrow, i=0..5
  const bf16* ag = h2 + (size_t)(b * 9216 + m0 + w * 48 + lrow) * K + c_sw * 8;
  // B staging: wave w stages rows w*32 + i*8 + lrow, i=0..3
  const bf16* bg = w3t + (size_t)(n0 + w * 32 + lrow) * K + c_sw * 8;
  short* al = A_lds + (size_t)w * 3072 + l * 8;
  short* bl = B_lds + (size_t)w * 2048 + l * 8;

  for (int kc = 0; kc < K; kc += 64) {
    if (kc) __syncthreads();
    #pragma unroll
    for (int i = 0; i < 6; ++i)
      gload_lds16(ag + kc + (size_t)i * 8 * K, al + i * 512);
    #pragma unroll
    for (int i = 0; i < 4; ++i)
      gload_lds16(bg + kc + (size_t)i * 8 * K, bl + i * 512);
    __syncthreads();
    #pragma unroll
    for (int ks = 0; ks < 64; ks += 32) {
      int cb = (ks >> 3) + quad;
      short8 af[6], bfr[4];
      #pragma unroll
      for (int mt = 0; mt < 6; ++mt) {
        int mr = mw + mt * 16 + l16;
        af[mt] = *(const short8*)&A_lds[mr * 64 + ((cb ^ (mr & 7)) * 8)];
      }
      #pragma unroll
      for (int nt = 0; nt < 4; ++nt) {
        int nr = nw + nt * 16 + l16;
        bfr[nt] = *(const short8*)&B_lds[nr * 64 + ((cb ^ (nr & 7)) * 8)];
      }
      #pragma unroll
      for (int mt = 0; mt < 6; ++mt)
        #pragma unroll
        for (int nt = 0; nt < 4; ++nt)
          acc[mt][nt] = __builtin_amdgcn_mfma_f32_16x16x32_bf16(af[mt], bfr[nt], acc[mt][nt], 0, 0, 0);
    }
  }
  #pragma unroll
  for (int nt = 0; nt < 4; ++nt) {
    int gcol = n0 + nw + nt * 16 + l16;
    float bias = g3b[gcol];
    float s2 = 0.f;
    #pragma unroll
    for (int mt = 0; mt < 6; ++mt)
      #pragma unroll
      for (int r = 0; r < 4; ++r)
        s2 += fmaxf(acc[mt][nt][r] + bias, 0.f);
    s2 += __shfl_xor(s2, 16, 64);
    s2 += __shfl_xor(s2, 32, 64);
    if (quad == 0) atomicAdd(&phi[b * 3072 + gcol], s2);
  }
}

extern "C" void kernel_launch(void* const* d_in, const int* in_sizes, int n_in,
                              void* d_out, int out_size, void* d_ws, size_t ws_size,
                              hipStream_t stream) {
  const float* x   = (const float*)d_in[0];
  const float* sen = (const float*)d_in[1];
  const float* w1  = (const float*)d_in[2];
  const float* b1  = (const float*)d_in[3];
  const float* w2  = (const float*)d_in[4];
  const float* b2  = (const float*)d_in[5];
  const float* w3  = (const float*)d_in[6];
  const float* b3  = (const float*)d_in[7];
  const float* w4  = (const float*)d_in[8];
  const float* b4  = (const float*)d_in[9];
  const float* g1w = (const float*)d_in[10];
  const float* g1b = (const float*)d_in[11];
  const float* g2w = (const float*)d_in[12];
  const float* g2b = (const float*)d_in[13];
  const float* g3w = (const float*)d_in[14];
  const float* g3b = (const float*)d_in[15];
  float* out = (float*)d_out;

  char* wsp = (char*)d_ws;
  size_t off = 0;
  auto alloc = [&](size_t bytes) {
    char* p = wsp + off;
    off += (bytes + 255) & ~(size_t)255;
    return (void*)p;
  };
  bf16* p1   = (bf16*)alloc((size_t)6144 * 64 * 2);
  bf16* p2   = (bf16*)alloc((size_t)1536 * 128 * 2);
  bf16* p3   = (bf16*)alloc((size_t)384 * 256 * 2);
  bf16* Fe   = (bf16*)alloc((size_t)448 * 576 * 2);
  bf16* wuv  = (bf16*)alloc((size_t)768 * 576 * 2);
  float* uvws = (float*)alloc((size_t)448 * 768 * 4);
  bf16* w2r  = (bf16*)alloc((size_t)128 * 576 * 2);
  bf16* w3r  = (bf16*)alloc((size_t)256 * 1152 * 2);
  bf16* w4r  = (bf16*)alloc((size_t)512 * 2304 * 2);
  bf16* w2t  = (bf16*)alloc((size_t)256 * 256 * 2);
  bf16* w3t  = (bf16*)alloc((size_t)3072 * 256 * 2);
  bf16* h2   = (bf16*)alloc((size_t)4 * 9216 * 256 * 2);
  float* zbuf = (float*)alloc((size_t)256);

  // prep (conv1pool + reorders + transposes + d_out zero), input-only deps
  prep_all_kernel<<<dim3(10433), 256, 0, stream>>>(x, w1, b1, p1, w2, w3, w4, g1w, sen, out,
                                                   w2r, w3r, w4r, wuv, Fe, zbuf, g2w, g3w, w2t, w3t);

  // encoder: implicit-im2col conv GEMMs with fused pooling (double-buffered)
  gemm_conv_kernel<6, true><<<dim3(2, 96), 256, 0, stream>>>(p1, w2r, b2, p2, (const bf16*)zbuf, 32, 48, 128, 128);
  gemm_conv_kernel<7, true><<<dim3(4, 24), 256, 0, stream>>>(p2, w3r, b3, p3, (const bf16*)zbuf, 16, 24, 256, 256);
  gemm_conv_kernel<8, false><<<dim3(8, 6), 256, 0, stream>>>(p3, w4r, b4, Fe, (const bf16*)zbuf, 8, 12, 512, 576);

  // head: u,v,ws GEMM (double-buffered), gemm2, gemm3 (192x128 tiles)
  gemm64_kernel<<<dim3(12, 7), 256, 0, stream>>>(Fe, wuv, uvws, 576, 768);
  gemm2_kernel<<<dim3(2, 72, 4), 256, 0, stream>>>(uvws, g1b, w2t, g2b, h2);
  gemm3_kernel<<<dim3(4608), 256, 0, stream>>>(h2, w3t, g3b, out);
}